// Round 1
// baseline (3104.586 us; speedup 1.0000x reference)
//
#include <hip/hip_runtime.h>
#include <hip/hip_bf16.h>

#define B_ 256
#define T_ 8
#define E_ 1024
#define H_ 1024
#define L_ 8
#define KD 2048   // E+H
#define ND 4096   // 4*H, gate-interleaved n = 4*j + g  (g: 0=u,1=f,2=o,3=c~)

#define BM 64
#define BN 128
#define BK 64

typedef __bf16 bf16x8 __attribute__((ext_vector_type(8)));
typedef float floatx4 __attribute__((ext_vector_type(4)));

struct bh4 { __hip_bfloat16 x, y, z, w; };  // 8-byte packed bf16 store

__device__ __forceinline__ float sigm(float x) { return 1.f / (1.f + __expf(-x)); }
// safe tanh: no inf/inf NaN for large |x|
__device__ __forceinline__ float tanh_(float x) { return 1.f - 2.f / (__expf(2.f * x) + 1.f); }

// ---------------------------------------------------------------------------
// P1: Wu/Wf/Wo/Wc (L,2048,1024) fp32  ->  WT[l][n][k] bf16, n = 4*j + g
// (N-major "B^T" layout so B-fragments are contiguous-K ds_read_b128)
// 32x32 tiled transpose per block. grid = L*4*64*32 = 65536 blocks.
// ---------------------------------------------------------------------------
__global__ __launch_bounds__(256) void prep_weights(
    const float* __restrict__ Wu, const float* __restrict__ Wf,
    const float* __restrict__ Wo, const float* __restrict__ Wc,
    __hip_bfloat16* __restrict__ WT)
{
    __shared__ float sm[32][33];
    int bid = blockIdx.x;
    int jt = bid & 31;
    int kt = (bid >> 5) & 63;
    int g  = (bid >> 11) & 3;
    int l  = bid >> 13;
    const float* src = (g == 0) ? Wu : (g == 1) ? Wf : (g == 2) ? Wo : Wc;
    int tid = threadIdx.x;
    int jl = tid & 31;
    int kl0 = tid >> 5;  // 0..7
#pragma unroll
    for (int r = 0; r < 4; ++r) {
        int kl = r * 8 + kl0;
        sm[kl][jl] = src[((size_t)(l * KD + kt * 32 + kl)) * 1024 + jt * 32 + jl];
    }
    __syncthreads();
    int jw = tid >> 3;         // 0..31
    int kc = (tid & 7) * 4;    // 0..28
    bh4 v;
    v.x = __float2bfloat16(sm[kc + 0][jw]);
    v.y = __float2bfloat16(sm[kc + 1][jw]);
    v.z = __float2bfloat16(sm[kc + 2][jw]);
    v.w = __float2bfloat16(sm[kc + 3][jw]);
    size_t n = (size_t)(jt * 32 + jw) * 4 + g;
    *(bh4*)&WT[((size_t)l * ND + n) * KD + kt * 32 + kc] = v;
}

// ---------------------------------------------------------------------------
// P2: x -> bf16; h0 -> bf16 hbuf0; c0 -> fp32 cbuf; biases -> interleaved bcat
// ---------------------------------------------------------------------------
__global__ __launch_bounds__(256) void prep_misc(
    const float* __restrict__ x,  const float* __restrict__ h0,
    const float* __restrict__ c0,
    const float* __restrict__ bu, const float* __restrict__ bfv,
    const float* __restrict__ bo, const float* __restrict__ bc,
    __hip_bfloat16* __restrict__ xbf, __hip_bfloat16* __restrict__ hb0,
    float* __restrict__ cbuf, float* __restrict__ bcat)
{
    size_t i = (size_t)blockIdx.x * 256 + threadIdx.x;
    const size_t NX = (size_t)B_ * T_ * E_;   // 2097152
    const size_t NH = (size_t)L_ * B_ * H_;   // 2097152
    if (i < NX) {
        xbf[i] = __float2bfloat16(x[i]);
    } else if (i < NX + NH) {
        size_t j = i - NX; hb0[j] = __float2bfloat16(h0[j]);
    } else if (i < NX + 2 * NH) {
        size_t j = i - NX - NH; cbuf[j] = c0[j];
    } else if (i < NX + 2 * NH + (size_t)L_ * ND) {
        size_t j = i - NX - 2 * NH;
        int l = (int)(j >> 12); int n = (int)(j & 4095);
        int jj = n >> 2; int g = n & 3;
        const float* bs = (g == 0) ? bu : (g == 1) ? bfv : (g == 2) ? bo : bc;
        bcat[j] = bs[l * 1024 + jj];
    }
}

// ---------------------------------------------------------------------------
// One diagonal d = t + l. cell index -> (t, l). 128 blocks per cell:
// m_blk in [0,4) x n_blk in [0,32).  GEMM 256x4096x2048 + fused LSTM epilogue.
//   A[b][k] = concat(inp, h[l])  (bf16), B^T = WT[l]  (bf16), acc fp32.
// h double-buffered on t-parity: read hbuf[t&1][l], prev-layer input is
// hbuf[(t+1)&1][l-1], write hbuf[(t+1)&1][l]. c in-place.
// ---------------------------------------------------------------------------
__global__ __launch_bounds__(256) void lstm_step(
    int d, int tmin,
    const __hip_bfloat16* __restrict__ xbf,
    const __hip_bfloat16* __restrict__ WT,
    const float* __restrict__ bcat,
    __hip_bfloat16* __restrict__ hb0,
    __hip_bfloat16* __restrict__ hb1,
    float* __restrict__ cbuf,
    float* __restrict__ out)
{
    // LDS: staging tiles (27648 B) reused as fp32 C tile (33792 B) in epilogue
    __shared__ __align__(16) char smraw[BM * (BN + 4) * 4];
    auto sA = (__hip_bfloat16(*)[BK + 8])smraw;                          // [64][72]
    auto sB = (__hip_bfloat16(*)[BK + 8])(smraw + BM * (BK + 8) * 2);    // [128][72]
    auto sC = (float(*)[BN + 4])smraw;                                   // [64][132]

    int cell = blockIdx.x >> 7;
    int tile = blockIdx.x & 127;
    int t = tmin + cell;
    int l = d - t;
    int m_blk = tile & 3;
    int n_blk = tile >> 2;

    const __hip_bfloat16* hread = (t & 1) ? hb1 : hb0;
    __hip_bfloat16*       hwrite = (t & 1) ? hb0 : hb1;

    const __hip_bfloat16* A1; int sA1;
    if (l == 0) { A1 = xbf + (size_t)t * E_;            sA1 = T_ * E_; }
    else        { A1 = hwrite + (size_t)(l - 1) * B_ * H_; sA1 = H_; }
    const __hip_bfloat16* A2 = hread + (size_t)l * B_ * H_;

    int tid  = threadIdx.x;
    int lane = tid & 63;
    int wid  = tid >> 6;
    int wm = (wid & 1) * 32;     // wave tile 32x64 in 2x2 wave grid
    int wn = (wid >> 1) * 64;
    int lr   = lane & 15;
    int quad = lane >> 4;

    floatx4 acc[2][4];
    floatx4 zero = {0.f, 0.f, 0.f, 0.f};
#pragma unroll
    for (int mi = 0; mi < 2; ++mi)
#pragma unroll
        for (int ni = 0; ni < 4; ++ni) acc[mi][ni] = zero;

    const __hip_bfloat16* Bbase = WT + ((size_t)l * ND + (size_t)n_blk * BN) * KD;

    for (int k0 = 0; k0 < KD; k0 += BK) {
        const __hip_bfloat16* aptr; int astr;
        if (k0 < E_) { aptr = A1 + k0;        astr = sA1; }
        else         { aptr = A2 + (k0 - E_); astr = H_; }
        uint4 av[2], bv[4];
#pragma unroll
        for (int i = 0; i < 2; ++i) {
            int cid = tid + i * 256;
            int row = cid >> 3;
            int kc  = (cid & 7) * 8;
            av[i] = *(const uint4*)(aptr + (size_t)(m_blk * BM + row) * astr + kc);
        }
#pragma unroll
        for (int i = 0; i < 4; ++i) {
            int cid = tid + i * 256;
            int row = cid >> 3;
            int kc  = (cid & 7) * 8;
            bv[i] = *(const uint4*)(Bbase + (size_t)row * KD + k0 + kc);
        }
        __syncthreads();   // previous iteration's LDS reads done
#pragma unroll
        for (int i = 0; i < 2; ++i) {
            int cid = tid + i * 256;
            *(uint4*)&sA[cid >> 3][(cid & 7) * 8] = av[i];
        }
#pragma unroll
        for (int i = 0; i < 4; ++i) {
            int cid = tid + i * 256;
            *(uint4*)&sB[cid >> 3][(cid & 7) * 8] = bv[i];
        }
        __syncthreads();
#pragma unroll
        for (int ks = 0; ks < 2; ++ks) {
            int ko = ks * 32 + quad * 8;
            bf16x8 af[2], bfr[4];
#pragma unroll
            for (int mi = 0; mi < 2; ++mi)
                af[mi] = *(const bf16x8*)&sA[wm + mi * 16 + lr][ko];
#pragma unroll
            for (int ni = 0; ni < 4; ++ni)
                bfr[ni] = *(const bf16x8*)&sB[wn + ni * 16 + lr][ko];
#pragma unroll
            for (int mi = 0; mi < 2; ++mi)
#pragma unroll
                for (int ni = 0; ni < 4; ++ni)
                    acc[mi][ni] = __builtin_amdgcn_mfma_f32_16x16x32_bf16(
                        af[mi], bfr[ni], acc[mi][ni], 0, 0, 0);
        }
    }

    // ---- epilogue: acc -> LDS (C layout: row = quad*4+reg, col = lane&15) ----
    __syncthreads();
#pragma unroll
    for (int mi = 0; mi < 2; ++mi)
#pragma unroll
        for (int ni = 0; ni < 4; ++ni)
#pragma unroll
            for (int r = 0; r < 4; ++r)
                sC[wm + mi * 16 + quad * 4 + r][wn + ni * 16 + lr] = acc[mi][ni][r];
    __syncthreads();

    float* outH  = out;
    float* outC  = out + (size_t)B_ * T_ * H_;
    float* outHt = out + 2 * (size_t)B_ * T_ * H_;
    float* outCt = outHt + (size_t)B_ * H_;

#pragma unroll
    for (int p = tid; p < BM * 32; p += 256) {   // 64 rows x 32 j per block
        int r  = p >> 5;
        int jj = p & 31;
        float4 v  = *(float4*)&sC[r][jj * 4];
        float4 bb = *(const float4*)&bcat[(size_t)l * ND + n_blk * BN + jj * 4];
        float u  = sigm(v.x + bb.x);
        float f  = sigm(v.y + bb.y);
        float o  = sigm(v.z + bb.z);
        float ct = tanh_(v.w + bb.w);
        int b = m_blk * BM + r;
        int j = n_blk * 32 + jj;
        size_t ci = ((size_t)l * B_ + b) * H_ + j;
        float cn = f * cbuf[ci] + u * ct;
        cbuf[ci] = cn;
        float hn = o * tanh_(cn);
        hwrite[ci] = __float2bfloat16(hn);
        if (l == L_ - 1) {
            size_t oi = ((size_t)b * T_ + t) * H_ + j;
            outH[oi] = hn;
            outC[oi] = cn;
            if (t == T_ - 1) {
                outHt[(size_t)b * H_ + j] = hn;
                outCt[(size_t)b * H_ + j] = cn;
            }
        }
    }
}

// ---------------------------------------------------------------------------
extern "C" void kernel_launch(void* const* d_in, const int* in_sizes, int n_in,
                              void* d_out, int out_size, void* d_ws, size_t ws_size,
                              hipStream_t stream)
{
    const float* x   = (const float*)d_in[0];
    const float* h0  = (const float*)d_in[1];
    const float* c0  = (const float*)d_in[2];
    const float* Wu  = (const float*)d_in[3];
    const float* bu  = (const float*)d_in[4];
    const float* Wf  = (const float*)d_in[5];
    const float* bfv = (const float*)d_in[6];
    const float* Wo  = (const float*)d_in[7];
    const float* bo  = (const float*)d_in[8];
    const float* Wc  = (const float*)d_in[9];
    const float* bc  = (const float*)d_in[10];
    float* out = (float*)d_out;

    char* ws = (char*)d_ws;
    // workspace layout (155,320,320 B total)
    __hip_bfloat16* WT   = (__hip_bfloat16*)(ws);                 // 134217728
    float*          bcat = (float*)(ws + 134217728);              //    131072
    __hip_bfloat16* xbf  = (__hip_bfloat16*)(ws + 134348800);     //   4194304
    __hip_bfloat16* hb0  = (__hip_bfloat16*)(ws + 138543104);     //   4194304
    __hip_bfloat16* hb1  = (__hip_bfloat16*)(ws + 142737408);     //   4194304
    float*          cbuf = (float*)(ws + 146931712);              //   8388608

    hipLaunchKernelGGL(prep_weights, dim3(65536), dim3(256), 0, stream,
                       Wu, Wf, Wo, Wc, WT);
    size_t n2 = (size_t)2097152 * 3 + (size_t)L_ * ND;
    hipLaunchKernelGGL(prep_misc, dim3((unsigned)((n2 + 255) / 256)), dim3(256), 0, stream,
                       x, h0, c0, bu, bfv, bo, bc, xbf, hb0, cbuf, bcat);

    for (int dg = 0; dg <= (T_ - 1) + (L_ - 1); ++dg) {
        int tmin = dg > L_ - 1 ? dg - (L_ - 1) : 0;
        int tmax = dg < T_ - 1 ? dg : T_ - 1;
        int nc = tmax - tmin + 1;
        hipLaunchKernelGGL(lstm_step, dim3(nc * 128), dim3(256), 0, stream,
                           dg, tmin, xbf, WT, bcat, hb0, hb1, cbuf, out);
    }
}

// Round 2
// 966.299 us; speedup vs baseline: 3.2129x; 3.2129x over previous
//
#include <hip/hip_runtime.h>
#include <hip/hip_bf16.h>

#define B_ 256
#define T_ 8
#define E_ 1024
#define H_ 1024
#define L_ 8
#define KD 2048   // E+H
#define ND 4096   // 4*H, gate-interleaved n = 4*j + g  (g: 0=u,1=f,2=o,3=c~)

#define BM 256
#define BN 128
#define BK 64
// per-buffer LDS: A 256x64 bf16 packed (32768 B) + B 128x64 bf16 (16384 B)
#define ABYTES 32768
#define BUFBYTES 49152

typedef __bf16 bf16x8 __attribute__((ext_vector_type(8)));
typedef float floatx4 __attribute__((ext_vector_type(4)));

struct bh4 { __hip_bfloat16 x, y, z, w; };

__device__ __forceinline__ float sigm(float x) { return 1.f / (1.f + __expf(-x)); }
__device__ __forceinline__ float tanh_(float x) { return 1.f - 2.f / (__expf(2.f * x) + 1.f); }

__device__ __forceinline__ void async16(const void* g, void* l) {
    __builtin_amdgcn_global_load_lds(
        (const __attribute__((address_space(1))) void*)g,
        (__attribute__((address_space(3))) void*)l, 16, 0, 0);
}

// ---------------------------------------------------------------------------
// P1: Wu/Wf/Wo/Wc (L,2048,1024) fp32 -> WT[l][n][k] bf16, n = 4*j + g
// ---------------------------------------------------------------------------
__global__ __launch_bounds__(256) void prep_weights(
    const float* __restrict__ Wu, const float* __restrict__ Wf,
    const float* __restrict__ Wo, const float* __restrict__ Wc,
    __hip_bfloat16* __restrict__ WT)
{
    __shared__ float sm[32][33];
    int bid = blockIdx.x;
    int jt = bid & 31;
    int kt = (bid >> 5) & 63;
    int g  = (bid >> 11) & 3;
    int l  = bid >> 13;
    const float* src = (g == 0) ? Wu : (g == 1) ? Wf : (g == 2) ? Wo : Wc;
    int tid = threadIdx.x;
    int jl = tid & 31;
    int kl0 = tid >> 5;
#pragma unroll
    for (int r = 0; r < 4; ++r) {
        int kl = r * 8 + kl0;
        sm[kl][jl] = src[((size_t)(l * KD + kt * 32 + kl)) * 1024 + jt * 32 + jl];
    }
    __syncthreads();
    int jw = tid >> 3;
    int kc = (tid & 7) * 4;
    bh4 v;
    v.x = __float2bfloat16(sm[kc + 0][jw]);
    v.y = __float2bfloat16(sm[kc + 1][jw]);
    v.z = __float2bfloat16(sm[kc + 2][jw]);
    v.w = __float2bfloat16(sm[kc + 3][jw]);
    size_t n = (size_t)(jt * 32 + jw) * 4 + g;
    *(bh4*)&WT[((size_t)l * ND + n) * KD + kt * 32 + kc] = v;
}

// ---------------------------------------------------------------------------
// P2: x -> bf16; h0 -> bf16; c0 -> fp32 cbuf; biases -> interleaved bcat
// ---------------------------------------------------------------------------
__global__ __launch_bounds__(256) void prep_misc(
    const float* __restrict__ x,  const float* __restrict__ h0,
    const float* __restrict__ c0,
    const float* __restrict__ bu, const float* __restrict__ bfv,
    const float* __restrict__ bo, const float* __restrict__ bc,
    __hip_bfloat16* __restrict__ xbf, __hip_bfloat16* __restrict__ hb0,
    float* __restrict__ cbuf, float* __restrict__ bcat)
{
    size_t i = (size_t)blockIdx.x * 256 + threadIdx.x;
    const size_t NX = (size_t)B_ * T_ * E_;
    const size_t NH = (size_t)L_ * B_ * H_;
    if (i < NX) {
        xbf[i] = __float2bfloat16(x[i]);
    } else if (i < NX + NH) {
        size_t j = i - NX; hb0[j] = __float2bfloat16(h0[j]);
    } else if (i < NX + 2 * NH) {
        size_t j = i - NX - NH; cbuf[j] = c0[j];
    } else if (i < NX + 2 * NH + (size_t)L_ * ND) {
        size_t j = i - NX - 2 * NH;
        int l = (int)(j >> 12); int n = (int)(j & 4095);
        int jj = n >> 2; int g = n & 3;
        const float* bs = (g == 0) ? bu : (g == 1) ? bfv : (g == 2) ? bo : bc;
        bcat[j] = bs[l * 1024 + jj];
    }
}

// ---------------------------------------------------------------------------
// One diagonal d = t + l. 32 blocks per cell (n_blk), BM=256 covers all batch.
// 512 threads = 8 waves (wave grid 4m x 2n, wave tile 64x64 of 16x16x32 MFMA).
// global_load_lds (16B) into XOR-swizzled LDS, double-buffered.
// ---------------------------------------------------------------------------
__global__ __launch_bounds__(512) void lstm_step(
    int d, int tmin,
    const __hip_bfloat16* __restrict__ xbf,
    const __hip_bfloat16* __restrict__ WT,
    const float* __restrict__ bcat,
    __hip_bfloat16* __restrict__ hb0,
    __hip_bfloat16* __restrict__ hb1,
    float* __restrict__ cbuf,
    float* __restrict__ out)
{
    __shared__ __align__(16) char smraw[2][BUFBYTES];   // 98304 B

    int cell = blockIdx.x >> 5;
    int nb   = blockIdx.x & 31;
    int t = tmin + cell;
    int l = d - t;

    const __hip_bfloat16* hread  = (t & 1) ? hb1 : hb0;
    __hip_bfloat16*       hwrite = (t & 1) ? hb0 : hb1;

    const __hip_bfloat16* A1; int sA1;
    if (l == 0) { A1 = xbf + (size_t)t * E_;               sA1 = T_ * E_; }
    else        { A1 = hwrite + (size_t)(l - 1) * B_ * H_; sA1 = H_; }
    const __hip_bfloat16* A2 = hread + (size_t)l * B_ * H_;
    const __hip_bfloat16* Bbase = WT + ((size_t)l * ND + (size_t)nb * BN) * KD;

    int tid  = threadIdx.x;
    int lane = tid & 63;
    int wid  = tid >> 6;
    int wm = (wid & 3) * 64;
    int wn = (wid >> 2) * 64;
    int lr   = lane & 15;
    int quad = lane >> 4;

    // ---- staging address precompute (fixed per thread across K) ----
    int srow = tid >> 3;                      // 0..63
    int c    = (tid & 7) ^ (srow & 7);        // XOR-swizzled 16B-chunk index
    const __hip_bfloat16* pA1[4];
    const __hip_bfloat16* pA2[4];
    const __hip_bfloat16* pB[2];
#pragma unroll
    for (int s = 0; s < 4; ++s) {
        int row = s * 64 + srow;              // 0..255
        pA1[s] = A1 + (size_t)row * sA1 + c * 8;
        pA2[s] = A2 + (size_t)row * H_ + c * 8 - E_;
    }
#pragma unroll
    for (int s = 0; s < 2; ++s) {
        int row = s * 64 + srow;              // 0..127
        pB[s] = Bbase + (size_t)row * KD + c * 8;
    }
    int ldsWaveOff = wid * 1024;              // bytes

    auto stage = [&](int k0, int buf) {
        char* dst = smraw[buf];
        bool first = (k0 < E_);
#pragma unroll
        for (int s = 0; s < 4; ++s) {
            const __hip_bfloat16* g = (first ? pA1[s] : pA2[s]) + k0;
            async16(g, dst + s * 8192 + ldsWaveOff);
        }
#pragma unroll
        for (int s = 0; s < 2; ++s) {
            async16(pB[s] + k0, dst + ABYTES + s * 8192 + ldsWaveOff);
        }
    };

    floatx4 acc[4][4];
    floatx4 zero = {0.f, 0.f, 0.f, 0.f};
#pragma unroll
    for (int mi = 0; mi < 4; ++mi)
#pragma unroll
        for (int ni = 0; ni < 4; ++ni) acc[mi][ni] = zero;

    stage(0, 0);
    __syncthreads();   // vmcnt drained -> buf0 resident

    for (int kt = 0; kt < KD / BK; ++kt) {
        int cur = kt & 1;
        if (kt < KD / BK - 1) stage((kt + 1) * BK, cur ^ 1);

        const __hip_bfloat16* sm = (const __hip_bfloat16*)smraw[cur];
        const __hip_bfloat16* smB = sm + ABYTES / 2;
#pragma unroll
        for (int ks = 0; ks < 2; ++ks) {
            int xo = (((ks * 4 + quad) ^ (lr & 7)) * 8);   // element offset in row
            bf16x8 af[4], bfr[4];
#pragma unroll
            for (int mi = 0; mi < 4; ++mi)
                af[mi] = *(const bf16x8*)&sm[(wm + mi * 16 + lr) * 64 + xo];
#pragma unroll
            for (int ni = 0; ni < 4; ++ni)
                bfr[ni] = *(const bf16x8*)&smB[(wn + ni * 16 + lr) * 64 + xo];
#pragma unroll
            for (int mi = 0; mi < 4; ++mi)
#pragma unroll
                for (int ni = 0; ni < 4; ++ni)
                    acc[mi][ni] = __builtin_amdgcn_mfma_f32_16x16x32_bf16(
                        af[mi], bfr[ni], acc[mi][ni], 0, 0, 0);
        }
        __syncthreads();   // readers done + next tile's DMA drained
    }

    // ---- epilogue: 4 chunks of 64 rows through LDS sC ----
    float* outH  = out;
    float* outC  = out + (size_t)B_ * T_ * H_;
    float* outHt = out + 2 * (size_t)B_ * T_ * H_;
    float* outCt = outHt + (size_t)B_ * H_;
    auto sC = (float(*)[BN + 4])smraw[0];   // 64 x 132 fp32 = 33792 B

    for (int q = 0; q < 4; ++q) {
        __syncthreads();
        if ((wid & 3) == q) {
#pragma unroll
            for (int mi = 0; mi < 4; ++mi)
#pragma unroll
                for (int ni = 0; ni < 4; ++ni)
#pragma unroll
                    for (int r = 0; r < 4; ++r)
                        sC[mi * 16 + quad * 4 + r][wn + ni * 16 + lr] = acc[mi][ni][r];
        }
        __syncthreads();
#pragma unroll
        for (int s = 0; s < 4; ++s) {
            int p = tid + s * 512;            // 0..2047
            int r  = p >> 5;
            int jj = p & 31;
            float4 v  = *(float4*)&sC[r][jj * 4];
            float4 bb = *(const float4*)&bcat[(size_t)l * ND + nb * BN + jj * 4];
            float u  = sigm(v.x + bb.x);
            float f  = sigm(v.y + bb.y);
            float o  = sigm(v.z + bb.z);
            float ct = tanh_(v.w + bb.w);
            int b = q * 64 + r;
            int j = nb * 32 + jj;
            size_t ci = ((size_t)l * B_ + b) * H_ + j;
            float cn = f * cbuf[ci] + u * ct;
            cbuf[ci] = cn;
            float hn = o * tanh_(cn);
            hwrite[ci] = __float2bfloat16(hn);
            if (l == L_ - 1) {
                size_t oi = ((size_t)b * T_ + t) * H_ + j;
                outH[oi] = hn;
                outC[oi] = cn;
                if (t == T_ - 1) {
                    outHt[(size_t)b * H_ + j] = hn;
                    outCt[(size_t)b * H_ + j] = cn;
                }
            }
        }
    }
}

// ---------------------------------------------------------------------------
extern "C" void kernel_launch(void* const* d_in, const int* in_sizes, int n_in,
                              void* d_out, int out_size, void* d_ws, size_t ws_size,
                              hipStream_t stream)
{
    const float* x   = (const float*)d_in[0];
    const float* h0  = (const float*)d_in[1];
    const float* c0  = (const float*)d_in[2];
    const float* Wu  = (const float*)d_in[3];
    const float* bu  = (const float*)d_in[4];
    const float* Wf  = (const float*)d_in[5];
    const float* bfv = (const float*)d_in[6];
    const float* Wo  = (const float*)d_in[7];
    const float* bo  = (const float*)d_in[8];
    const float* Wc  = (const float*)d_in[9];
    const float* bc  = (const float*)d_in[10];
    float* out = (float*)d_out;

    char* ws = (char*)d_ws;
    __hip_bfloat16* WT   = (__hip_bfloat16*)(ws);                 // 134217728
    float*          bcat = (float*)(ws + 134217728);              //    131072
    __hip_bfloat16* xbf  = (__hip_bfloat16*)(ws + 134348800);     //   4194304
    __hip_bfloat16* hb0  = (__hip_bfloat16*)(ws + 138543104);     //   4194304
    __hip_bfloat16* hb1  = (__hip_bfloat16*)(ws + 142737408);     //   4194304
    float*          cbuf = (float*)(ws + 146931712);              //   8388608

    hipLaunchKernelGGL(prep_weights, dim3(65536), dim3(256), 0, stream,
                       Wu, Wf, Wo, Wc, WT);
    size_t n2 = (size_t)2097152 * 3 + (size_t)L_ * ND;
    hipLaunchKernelGGL(prep_misc, dim3((unsigned)((n2 + 255) / 256)), dim3(256), 0, stream,
                       x, h0, c0, bu, bfv, bo, bc, xbf, hb0, cbuf, bcat);

    for (int dg = 0; dg <= (T_ - 1) + (L_ - 1); ++dg) {
        int tmin = dg > L_ - 1 ? dg - (L_ - 1) : 0;
        int tmax = dg < T_ - 1 ? dg : T_ - 1;
        int nc = tmax - tmin + 1;
        hipLaunchKernelGGL(lstm_step, dim3(nc * 32), dim3(512), 0, stream,
                           dg, tmin, xbf, WT, bcat, hb0, hb1, cbuf, out);
    }
}